// Round 10
// baseline (172.589 us; speedup 1.0000x reference)
//
#include <hip/hip_runtime.h>
#include <hip/hip_bf16.h>
#include <cstdint>
#include <cstddef>

// Problem constants (B=2, N=2048, D=1024, H=16, DH=64, window +-64)
#define BB 2
#define NN 2048
#define DD 1024
#define HH 16
#define DHH 64
#define SCALE 0.125f

typedef _Float16 f16x8 __attribute__((ext_vector_type(8)));
typedef _Float16 f16x4 __attribute__((ext_vector_type(4)));
typedef float f32x4 __attribute__((ext_vector_type(4)));

#define AS1(p) ((__attribute__((address_space(1))) void*)(p))
#define AS3(p) ((__attribute__((address_space(3))) void*)(p))

// ---------------- fused prep: x cast + both weight transposes, one launch ----------------
__global__ __launch_bounds__(256) void prep(const float* __restrict__ x, _Float16* __restrict__ x_h,
                                            const float* __restrict__ Wqkv, _Float16* __restrict__ Wqkv_t,
                                            const float* __restrict__ Wout, _Float16* __restrict__ Wout_t) {
    __shared__ float tile[32][33];
    int bx = blockIdx.x, tid = threadIdx.x;
    if (bx < 2048) {
        int i = bx * 2048 + tid * 8;
        f32x4 a = *(const f32x4*)(x + i);
        f32x4 b = *(const f32x4*)(x + i + 4);
        f16x8 o;
        o[0] = (_Float16)a[0]; o[1] = (_Float16)a[1]; o[2] = (_Float16)a[2]; o[3] = (_Float16)a[3];
        o[4] = (_Float16)b[0]; o[5] = (_Float16)b[1]; o[6] = (_Float16)b[2]; o[7] = (_Float16)b[3];
        *(f16x8*)(x_h + i) = o;
        return;
    }
    const float* in; _Float16* out; int C, tc, tr;
    if (bx < 5120) { int t = bx - 2048; C = 3 * DD; in = Wqkv; out = Wqkv_t; tc = t % 96; tr = t / 96; }
    else           { int t = bx - 5120; C = DD;     in = Wout; out = Wout_t; tc = t % 32; tr = t / 32; }
    int R = DD;
    int txx = tid & 31, ty = tid >> 5;
    int r0 = tr * 32, c0 = tc * 32;
#pragma unroll
    for (int i = 0; i < 32; i += 8)
        tile[ty + i][txx] = in[(size_t)(r0 + ty + i) * C + (c0 + txx)];
    __syncthreads();
#pragma unroll
    for (int i = 0; i < 32; i += 8)
        out[(size_t)(c0 + ty + i) * R + (r0 + txx)] = (_Float16)tile[txx][ty + i];
}

// ---------------- QKV GEMM: 256 thr, 256x128 tile, BK=64, swizzled LDS ----------------
// 4 waves; wave w owns rows [w*64, w*64+64) x all 128 cols (acc 8x4 f32x4 = 128 VGPR).
// Per iter per block: A 32 KB + B 16 KB staged (48 KB) for 256 wave-MFMAs -- 187 B/MFMA
// vs R6's 250 B/MFMA (staged total 295 MB vs 393 MB). Barrier width stays 4 waves.
// XOR swizzle: LDS slot c of row r holds global chunk c^(r&7); staging lane L reads
// global chunk (L&7)^(L>>3) (wave/pass-invariant -> global_load_lds-legal).
// Epilogue per region (block-uniform bn>>10): q/k use SWAPPED mfma operand order
// (D-row = out-col) -> f16x4 row-stores; v normal -> f16x4 into vt_h[(b,h,dh)][n].
__global__ __launch_bounds__(256) void gemm_qkv(const _Float16* __restrict__ A,
                                                const _Float16* __restrict__ Bt,
                                                const float* __restrict__ bias,
                                                _Float16* __restrict__ q_h,
                                                _Float16* __restrict__ k_h,
                                                _Float16* __restrict__ vt_h) {
    const int K = DD;
    __shared__ __align__(16) _Float16 As[256 * 64];   // 32 KB
    __shared__ __align__(16) _Float16 Bs[128 * 64];   // 16 KB
    int id = blockIdx.x;
    int xcd = id & 7, j = id >> 3;            // j in [0,48)
    int bn = (xcd * 3 + j % 3) * 128;         // 24 n-panels of 128
    int bm = (j / 3) * 256;                   // 16 m-strips of 256
    int tid = threadIdx.x;
    int wave = tid >> 6, lane = tid & 63;
    int wm = wave * 64;                       // wave's row range within tile
    int lhi = lane >> 4, llo = lane & 15;

    f32x4 acc[8][4] = {};   // SWAP: [nt][mt] = C^T tile; normal: [nt][mt] with D-row=token

    int srowA = wave * 64 + (lane >> 3);      // A: 8 passes of 8 rows per wave
    int srowB = wave * 32 + (lane >> 3);      // B: 4 passes of 8 rows per wave
    int scol = ((lane & 7) ^ (lane >> 3)) * 8;
    const _Float16* gA = A + (size_t)(bm + srowA) * K + scol;
    const _Float16* gB = Bt + (size_t)(bn + srowB) * K + scol;
    _Float16* lA = As + wave * 4096 + lane * 8;
    _Float16* lB = Bs + wave * 2048 + lane * 8;

    int region = bn >> 10;                    // block-uniform: 0=q, 1=k, 2=v
    bool swap = (region != 2);

    for (int k0 = 0; k0 < K; k0 += 64) {
        __syncthreads();
#pragma unroll
        for (int p = 0; p < 8; ++p)
            __builtin_amdgcn_global_load_lds(AS1(gA + (size_t)p * 8 * K + k0), AS3(lA + p * 512), 16, 0, 0);
#pragma unroll
        for (int p = 0; p < 4; ++p)
            __builtin_amdgcn_global_load_lds(AS1(gB + (size_t)p * 8 * K + k0), AS3(lB + p * 512), 16, 0, 0);
        __syncthreads();

#pragma unroll
        for (int ks = 0; ks < 2; ++ks) {
            f16x8 af[4], bf[8];
            int swz = (((ks * 4 + lhi) ^ (llo & 7)) * 8);
#pragma unroll
            for (int mt = 0; mt < 4; ++mt)
                af[mt] = *(const f16x8*)(As + (wm + mt * 16 + llo) * 64 + swz);
#pragma unroll
            for (int nt = 0; nt < 8; ++nt)
                bf[nt] = *(const f16x8*)(Bs + (nt * 16 + llo) * 64 + swz);
            if (swap) {
#pragma unroll
                for (int nt = 0; nt < 8; ++nt)
#pragma unroll
                    for (int mt = 0; mt < 4; ++mt)
                        acc[nt][mt] = __builtin_amdgcn_mfma_f32_16x16x32_f16(bf[nt], af[mt], acc[nt][mt], 0, 0, 0);
            } else {
#pragma unroll
                for (int nt = 0; nt < 8; ++nt)
#pragma unroll
                    for (int mt = 0; mt < 4; ++mt)
                        acc[nt][mt] = __builtin_amdgcn_mfma_f32_16x16x32_f16(af[mt], bf[nt], acc[nt][mt], 0, 0, 0);
            }
        }
    }

    if (region == 2) {
        // normal: D-row = token (wm+mt*16+lhi*4+r), D-col = out-col (bn+nt*16+llo)
#pragma unroll
        for (int nt = 0; nt < 8; ++nt) {
            int col = bn + nt * 16 + llo;
            float bv = bias[col];
            int c = col & 1023;
            int h = c >> 6, dh = c & 63;
#pragma unroll
            for (int mt = 0; mt < 4; ++mt) {
                int row = bm + wm + mt * 16 + lhi * 4;
                int b = row >> 11, n = row & 2047;
                f16x4 v4;
#pragma unroll
                for (int r = 0; r < 4; ++r) v4[r] = (_Float16)(acc[nt][mt][r] + bv);
                *(f16x4*)(vt_h + ((size_t)((b * HH + h) * DHH + dh)) * NN + n) = v4;
            }
        }
    } else {
        // swapped: D-row = out-col, D-col = token -> lane holds 4 consecutive out-cols
        _Float16* dst0 = (region == 0 ? q_h : k_h);
#pragma unroll
        for (int nt = 0; nt < 8; ++nt) {
            int cbase = bn + nt * 16 + lhi * 4;
            f32x4 b4 = *(const f32x4*)(bias + cbase);
            int c = cbase & 1023;
#pragma unroll
            for (int mt = 0; mt < 4; ++mt) {
                int t = bm + wm + mt * 16 + llo;
                int b = t >> 11, n = t & 2047;
                f16x4 v4;
#pragma unroll
                for (int r = 0; r < 4; ++r) v4[r] = (_Float16)(acc[nt][mt][r] + b4[r]);
                *(f16x4*)(dst0 + (size_t)(b * NN + n) * DD + c) = v4;
            }
        }
    }
}

// ---------------- R6 LDS K-loop (gemm_out) ----------------
template <bool SWAP, int MT>
__device__ __forceinline__ void gemm_kloop(const _Float16* __restrict__ gA,
                                           const _Float16* __restrict__ gB,
                                           _Float16* lA, _Float16* lB,
                                           const _Float16* As, const _Float16* Bs,
                                           int wm, int wn, int llo, int lhi, int K,
                                           f32x4 acc[][MT > 4 ? MT : 4]) {
    for (int k0 = 0; k0 < K; k0 += 64) {
        __syncthreads();
#pragma unroll
        for (int p = 0; p < MT; ++p)
            __builtin_amdgcn_global_load_lds(AS1(gA + (size_t)p * 8 * K + k0), AS3(lA + p * 512), 16, 0, 0);
#pragma unroll
        for (int p = 0; p < 4; ++p)
            __builtin_amdgcn_global_load_lds(AS1(gB + (size_t)p * 8 * K + k0), AS3(lB + p * 512), 16, 0, 0);
        __syncthreads();

#pragma unroll
        for (int ks = 0; ks < 2; ++ks) {
            f16x8 af[MT], bf[4];
            int swz = (((ks * 4 + lhi) ^ (llo & 7)) * 8);
#pragma unroll
            for (int mt = 0; mt < MT; ++mt)
                af[mt] = *(const f16x8*)(As + (wm + mt * 16 + llo) * 64 + swz);
#pragma unroll
            for (int nt = 0; nt < 4; ++nt)
                bf[nt] = *(const f16x8*)(Bs + (wn + nt * 16 + llo) * 64 + swz);
            if (SWAP) {
#pragma unroll
                for (int nt = 0; nt < 4; ++nt)
#pragma unroll
                    for (int mt = 0; mt < MT; ++mt)
                        acc[nt][mt] = __builtin_amdgcn_mfma_f32_16x16x32_f16(bf[nt], af[mt], acc[nt][mt], 0, 0, 0);
            } else {
#pragma unroll
                for (int mt = 0; mt < MT; ++mt)
#pragma unroll
                    for (int nt = 0; nt < 4; ++nt)
                        acc[mt][nt] = __builtin_amdgcn_mfma_f32_16x16x32_f16(af[mt], bf[nt], acc[mt][nt], 0, 0, 0);
            }
        }
    }
}

// ---------------- out-proj GEMM (R6 version: BM=64, SWAP epilogue, 24 KB LDS) ----------------
__global__ __launch_bounds__(256) void gemm_out(const _Float16* __restrict__ A,
                                                const _Float16* __restrict__ Bt,
                                                const float* __restrict__ bias,
                                                float* __restrict__ Cf) {
    const int K = DD, N = DD;
    __shared__ __align__(16) _Float16 As[64 * 64];
    __shared__ __align__(16) _Float16 Bs[128 * 64];
    int id = blockIdx.x;
    int xcd = id & 7, j = id >> 3;
    int bm = (xcd * 8 + (j >> 3)) * 64;
    int bn = (j & 7) * 128;
    int tid = threadIdx.x;
    int wave = tid >> 6, lane = tid & 63;
    int wm = (wave >> 1) * 32, wn = (wave & 1) * 64;
    int lhi = lane >> 4, llo = lane & 15;

    f32x4 acc[4][4] = {};   // [nt][mt], mt<2 used

    int srowA = wave * 16 + (lane >> 3);
    int srowB = wave * 32 + (lane >> 3);
    int scol = ((lane & 7) ^ (lane >> 3)) * 8;
    const _Float16* gA = A + (size_t)(bm + srowA) * K + scol;
    const _Float16* gB = Bt + (size_t)(bn + srowB) * K + scol;
    _Float16* lA = As + wave * 1024 + lane * 8;
    _Float16* lB = Bs + wave * 2048 + lane * 8;

    gemm_kloop<true, 2>(gA, gB, lA, lB, As, Bs, wm, wn, llo, lhi, K,
                        (f32x4(*)[4])acc);

#pragma unroll
    for (int nt = 0; nt < 4; ++nt) {
        int cbase = bn + wn + nt * 16 + lhi * 4;
        f32x4 b4 = *(const f32x4*)(bias + cbase);
#pragma unroll
        for (int mt = 0; mt < 2; ++mt) {
            int t = bm + wm + mt * 16 + llo;
            f32x4 v4;
#pragma unroll
            for (int r = 0; r < 4; ++r) v4[r] = acc[nt][mt][r] + b4[r];
            *(f32x4*)(Cf + (size_t)t * N + cbase) = v4;
        }
    }
}

// ---------------- windowed attention via MFMA (Ks/P LDS overlay: 50 KB, 3 blocks/CU) ----------------
#define KP 64
#define PP 200   // P stride: 400B (16B-aligned), rows 4 banks apart
#define VP 200
__global__ __launch_bounds__(256) void local_attn(const _Float16* __restrict__ q_h,
                                                  const _Float16* __restrict__ k_h,
                                                  const _Float16* __restrict__ vt_h,
                                                  _Float16* __restrict__ outh) {
    __shared__ __align__(16) _Float16 KsPs[64 * PP];  // 25600 B: Ks[192*64] overlaid by P[64*PP]
    __shared__ __align__(16) _Float16 Vt[64 * VP];    // 25600 B
    _Float16* Ks = KsPs;
    _Float16* Ps = KsPs;
    int tid = threadIdx.x;
    int id = blockIdx.x;
    int xcd = id & 7, j = id >> 3;
    int i0 = (xcd * 4 + (j & 3)) * 64;
    int hb = j >> 2;
    int h = hb & 15, b = hb >> 4;

    int wave = tid >> 6, lane = tid & 63;
    int llo = lane & 15, lhi = lane >> 4;

    // --- async K staging: rows j = i0-64 .. i0+127 from k_h[b][j][h*64..] ---
    {
        int srow = lane >> 3;
        int chunk = ((lane & 7) ^ (lane >> 3)) * 8;
        const _Float16* kb = k_h + (size_t)(b * NN) * DD + h * DHH + chunk;
#pragma unroll
        for (int q = 0; q < 6; ++q) {
            int p = wave * 6 + q;
            int jj = i0 - 64 + p * 8 + srow;   // may be OOR: mapped garbage, masked later
            __builtin_amdgcn_global_load_lds(AS1(kb + (ptrdiff_t)jj * DD), AS3(Ks + p * 512 + lane * 8), 16, 0, 0);
        }
    }

    // --- V^T staging: plain copy of 64 dh-rows x 192 tokens from vt_h ---
    {
        const _Float16* vb = vt_h + (size_t)((b * HH + h) * DHH) * NN + (i0 - 64);
        for (int u = tid; u < 1536; u += 256) {
            int d = u / 24, c = u % 24;
            f16x8 vv = *(const f16x8*)(vb + (ptrdiff_t)d * NN + c * 8);
            *(f16x8*)(Vt + d * VP + c * 8) = vv;
        }
    }

    // --- Q fragments straight from global ---
    int qrow = wave * 16 + llo;
    int qi = i0 + qrow;
    const _Float16* qp = q_h + (size_t)(b * NN + qi) * DD + h * DHH;
    f16x8 qf0 = *(const f16x8*)(qp + lhi * 8);
    f16x8 qf1 = *(const f16x8*)(qp + 32 + lhi * 8);
    __syncthreads();

    // --- S^T = K @ Q^T (swizzled Ks reads; row&7 == llo&7) ---
    float sc[12][4];
#pragma unroll
    for (int mt = 0; mt < 12; ++mt) {
        const _Float16* kr = Ks + (mt * 16 + llo) * 64;
        f16x8 kf0 = *(const f16x8*)(kr + ((lhi ^ (llo & 7)) * 8));
        f16x8 kf1 = *(const f16x8*)(kr + (((lhi + 4) ^ (llo & 7)) * 8));
        f32x4 a = {0.f, 0.f, 0.f, 0.f};
        a = __builtin_amdgcn_mfma_f32_16x16x32_f16(kf0, qf0, a, 0, 0, 0);
        a = __builtin_amdgcn_mfma_f32_16x16x32_f16(kf1, qf1, a, 0, 0, 0);
#pragma unroll
        for (int r = 0; r < 4; ++r) sc[mt][r] = a[r];
    }
    __syncthreads();   // all waves done reading Ks; its LDS is now P's

    // --- masked softmax over 192 slots of query qi ---
    float m = -1e30f;
#pragma unroll
    for (int mt = 0; mt < 12; ++mt)
#pragma unroll
        for (int r = 0; r < 4; ++r) {
            int sidx = mt * 16 + lhi * 4 + r;
            int jj = i0 - 64 + sidx;
            int dj = jj - qi;
            bool valid = (jj >= 0) && (jj < NN) && (dj <= 64) && (dj >= -64);
            float v = valid ? sc[mt][r] * SCALE : -1e30f;   // select: garbage never propagates
            sc[mt][r] = v;
            m = fmaxf(m, v);
        }
    m = fmaxf(m, __shfl_xor(m, 16, 64));
    m = fmaxf(m, __shfl_xor(m, 32, 64));
    float l = 0.f;
#pragma unroll
    for (int mt = 0; mt < 12; ++mt)
#pragma unroll
        for (int r = 0; r < 4; ++r) {
            float e = __expf(sc[mt][r] - m);
            sc[mt][r] = e;
            l += e;
        }
    l += __shfl_xor(l, 16, 64);
    l += __shfl_xor(l, 32, 64);
    float invl = 1.f / l;

    // --- write normalized P rows (overlays Ks; own rows -> wave-local wait) ---
#pragma unroll
    for (int mt = 0; mt < 12; ++mt) {
        f16x4 pv;
#pragma unroll
        for (int r = 0; r < 4; ++r) pv[r] = (_Float16)(sc[mt][r] * invl);
        *(f16x4*)(Ps + qrow * PP + mt * 16 + lhi * 4) = pv;
    }
    __asm__ volatile("s_waitcnt lgkmcnt(0)" ::: "memory");  // wave-local P write->read

    // --- O = P @ V ---
    f32x4 oacc[4] = {};
#pragma unroll
    for (int ks = 0; ks < 6; ++ks) {
        f16x8 pf = *(const f16x8*)(Ps + (wave * 16 + llo) * PP + ks * 32 + lhi * 8);
#pragma unroll
        for (int nt = 0; nt < 4; ++nt) {
            f16x8 vf = *(const f16x8*)(Vt + (nt * 16 + llo) * VP + ks * 32 + lhi * 8);
            oacc[nt] = __builtin_amdgcn_mfma_f32_16x16x32_f16(pf, vf, oacc[nt], 0, 0, 0);
        }
    }

    // --- epilogue: col=llo=dh, row=lhi*4+r=query ---
    _Float16* orow = outh + (size_t)(b * NN) * DD + h * DHH;
#pragma unroll
    for (int nt = 0; nt < 4; ++nt)
#pragma unroll
        for (int r = 0; r < 4; ++r) {
            int q = wave * 16 + lhi * 4 + r;
            int d = nt * 16 + llo;
            orow[(size_t)(i0 + q) * DD + d] = (_Float16)oacc[nt][r];
        }
}

// ---------------- launch ----------------
extern "C" void kernel_launch(void* const* d_in, const int* in_sizes, int n_in,
                              void* d_out, int out_size, void* d_ws, size_t ws_size,
                              hipStream_t stream) {
    const float* x    = (const float*)d_in[0];
    const float* Wqkv = (const float*)d_in[1];
    const float* bqkv = (const float*)d_in[2];
    const float* Wout = (const float*)d_in[3];
    const float* bout = (const float*)d_in[4];
    float* out = (float*)d_out;

    char* ws = (char*)d_ws;
    _Float16* x_h    = (_Float16*)(ws);                              //  8 MB [4096][1024]
    _Float16* Wqkv_t = (_Float16*)(ws + (size_t)8  * 1024 * 1024);   //  6 MB [3072][1024]
    _Float16* Wout_t = (_Float16*)(ws + (size_t)14 * 1024 * 1024);   //  2 MB [1024][1024]
    _Float16* q_h    = (_Float16*)(ws + (size_t)16 * 1024 * 1024);   //  8 MB [2][2048][1024]
    _Float16* k_h    = (_Float16*)(ws + (size_t)24 * 1024 * 1024);   //  8 MB [2][2048][1024]
    _Float16* vt_h   = (_Float16*)(ws + (size_t)32 * 1024 * 1024);   //  8 MB [2*16*64][2048]
    _Float16* attn_h = (_Float16*)(ws + (size_t)40 * 1024 * 1024);   //  8 MB [4096][1024]

    prep<<<6144, 256, 0, stream>>>(x, x_h, Wqkv, Wqkv_t, Wout, Wout_t);

    gemm_qkv<<<384, 256, 0, stream>>>(x_h, Wqkv_t, bqkv, q_h, k_h, vt_h);

    local_attn<<<1024, 256, 0, stream>>>(q_h, k_h, vt_h, attn_h);

    gemm_out<<<512, 256, 0, stream>>>(attn_h, Wout_t, bout, out);
}

// Round 11
// 155.762 us; speedup vs baseline: 1.1080x; 1.1080x over previous
//
#include <hip/hip_runtime.h>
#include <hip/hip_bf16.h>
#include <cstdint>
#include <cstddef>

// Problem constants (B=2, N=2048, D=1024, H=16, DH=64, window +-64)
#define BB 2
#define NN 2048
#define DD 1024
#define HH 16
#define DHH 64
#define SCALE 0.125f

typedef _Float16 f16x8 __attribute__((ext_vector_type(8)));
typedef _Float16 f16x4 __attribute__((ext_vector_type(4)));
typedef float f32x4 __attribute__((ext_vector_type(4)));

#define AS1(p) ((__attribute__((address_space(1))) void*)(p))
#define AS3(p) ((__attribute__((address_space(3))) void*)(p))

// ---------------- fused prep: x cast + both weight transposes, one launch ----------------
__global__ __launch_bounds__(256) void prep(const float* __restrict__ x, _Float16* __restrict__ x_h,
                                            const float* __restrict__ Wqkv, _Float16* __restrict__ Wqkv_t,
                                            const float* __restrict__ Wout, _Float16* __restrict__ Wout_t) {
    __shared__ float tile[32][33];
    int bx = blockIdx.x, tid = threadIdx.x;
    if (bx < 2048) {
        int i = bx * 2048 + tid * 8;
        f32x4 a = *(const f32x4*)(x + i);
        f32x4 b = *(const f32x4*)(x + i + 4);
        f16x8 o;
        o[0] = (_Float16)a[0]; o[1] = (_Float16)a[1]; o[2] = (_Float16)a[2]; o[3] = (_Float16)a[3];
        o[4] = (_Float16)b[0]; o[5] = (_Float16)b[1]; o[6] = (_Float16)b[2]; o[7] = (_Float16)b[3];
        *(f16x8*)(x_h + i) = o;
        return;
    }
    const float* in; _Float16* out; int C, tc, tr;
    if (bx < 5120) { int t = bx - 2048; C = 3 * DD; in = Wqkv; out = Wqkv_t; tc = t % 96; tr = t / 96; }
    else           { int t = bx - 5120; C = DD;     in = Wout; out = Wout_t; tc = t % 32; tr = t / 32; }
    int R = DD;
    int txx = tid & 31, ty = tid >> 5;
    int r0 = tr * 32, c0 = tc * 32;
#pragma unroll
    for (int i = 0; i < 32; i += 8)
        tile[ty + i][txx] = in[(size_t)(r0 + ty + i) * C + (c0 + txx)];
    __syncthreads();
#pragma unroll
    for (int i = 0; i < 32; i += 8)
        out[(size_t)(c0 + ty + i) * R + (r0 + txx)] = (_Float16)tile[txx][ty + i];
}

// ---------------- shared K-loop body (R6: single-buffer, BK=64, XOR-swizzled LDS) ----------------
// LDS slot c_l of row r holds global chunk c_l^(r&7); staging lane L reads global
// chunk (L&7)^(L>>3) (wave/pass-invariant -> global_load_lds uniform-base-legal).
// Measured best point of this family (R6): do NOT dbuf, widen, or fatten (R7-R10 all regressed).
template <bool SWAP, int MT>
__device__ __forceinline__ void gemm_kloop(const _Float16* __restrict__ gA,
                                           const _Float16* __restrict__ gB,
                                           _Float16* lA, _Float16* lB,
                                           const _Float16* As, const _Float16* Bs,
                                           int wm, int wn, int llo, int lhi, int K,
                                           f32x4 acc[][MT > 4 ? MT : 4]) {
    for (int k0 = 0; k0 < K; k0 += 64) {
        __syncthreads();
#pragma unroll
        for (int p = 0; p < MT; ++p)
            __builtin_amdgcn_global_load_lds(AS1(gA + (size_t)p * 8 * K + k0), AS3(lA + p * 512), 16, 0, 0);
#pragma unroll
        for (int p = 0; p < 4; ++p)
            __builtin_amdgcn_global_load_lds(AS1(gB + (size_t)p * 8 * K + k0), AS3(lB + p * 512), 16, 0, 0);
        __syncthreads();

#pragma unroll
        for (int ks = 0; ks < 2; ++ks) {
            f16x8 af[MT], bf[4];
            int swz = (((ks * 4 + lhi) ^ (llo & 7)) * 8);
#pragma unroll
            for (int mt = 0; mt < MT; ++mt)
                af[mt] = *(const f16x8*)(As + (wm + mt * 16 + llo) * 64 + swz);
#pragma unroll
            for (int nt = 0; nt < 4; ++nt)
                bf[nt] = *(const f16x8*)(Bs + (wn + nt * 16 + llo) * 64 + swz);
            if (SWAP) {
#pragma unroll
                for (int nt = 0; nt < 4; ++nt)
#pragma unroll
                    for (int mt = 0; mt < MT; ++mt)
                        acc[nt][mt] = __builtin_amdgcn_mfma_f32_16x16x32_f16(bf[nt], af[mt], acc[nt][mt], 0, 0, 0);
            } else {
#pragma unroll
                for (int mt = 0; mt < MT; ++mt)
#pragma unroll
                    for (int nt = 0; nt < 4; ++nt)
                        acc[mt][nt] = __builtin_amdgcn_mfma_f32_16x16x32_f16(af[mt], bf[nt], acc[mt][nt], 0, 0, 0);
            }
        }
    }
}

// ---------------- QKV GEMM (exact R6): 128x128 tile, grid 768 XCD-swizzled ----------------
// q/k regions use SWAP (C^T) -> f16x4 row-stores; v region normal -> f16x4 into vt_h.
__global__ __launch_bounds__(256) void gemm_qkv(const _Float16* __restrict__ A,
                                                const _Float16* __restrict__ Bt,
                                                const float* __restrict__ bias,
                                                _Float16* __restrict__ q_h,
                                                _Float16* __restrict__ k_h,
                                                _Float16* __restrict__ vt_h) {
    const int K = DD;
    __shared__ __align__(16) _Float16 As[128 * 64];
    __shared__ __align__(16) _Float16 Bs[128 * 64];
    int id = blockIdx.x;
    int xcd = id & 7, j = id >> 3;
    int bn = (xcd * 3 + j % 3) * 128;
    int bm = (j / 3) * 128;
    int tid = threadIdx.x;
    int wave = tid >> 6, lane = tid & 63;
    int wm = (wave >> 1) * 64, wn = (wave & 1) * 64;
    int lhi = lane >> 4, llo = lane & 15;

    f32x4 acc[4][4] = {};

    int srow = wave * 32 + (lane >> 3);
    int scol = ((lane & 7) ^ (lane >> 3)) * 8;
    const _Float16* gA = A + (size_t)(bm + srow) * K + scol;
    const _Float16* gB = Bt + (size_t)(bn + srow) * K + scol;
    _Float16* lA = As + wave * 2048 + lane * 8;
    _Float16* lB = Bs + wave * 2048 + lane * 8;

    int region = bn >> 10;            // block-uniform: 0=q, 1=k, 2=v
    if (region == 2) {
        gemm_kloop<false, 4>(gA, gB, lA, lB, As, Bs, wm, wn, llo, lhi, K, acc);
        // normal: lane = 4 consecutive tokens of one dh col -> vt_h[(b,h,dh)][n..n+3]
#pragma unroll
        for (int nt = 0; nt < 4; ++nt) {
            int col = bn + wn + nt * 16 + llo;
            float bv = bias[col];
            int c = col & 1023;
            int h = c >> 6, dh = c & 63;
#pragma unroll
            for (int mt = 0; mt < 4; ++mt) {
                int row = bm + wm + mt * 16 + lhi * 4;
                int b = row >> 11, n = row & 2047;
                f16x4 v4;
#pragma unroll
                for (int r = 0; r < 4; ++r) v4[r] = (_Float16)(acc[mt][nt][r] + bv);
                *(f16x4*)(vt_h + ((size_t)((b * HH + h) * DHH + dh)) * NN + n) = v4;
            }
        }
    } else {
        gemm_kloop<true, 4>(gA, gB, lA, lB, As, Bs, wm, wn, llo, lhi, K, acc);
        // swapped: lane = 4 consecutive out-cols of one token -> f16x4 row-stores
        _Float16* dst0 = (region == 0 ? q_h : k_h);
#pragma unroll
        for (int nt = 0; nt < 4; ++nt) {
            int cbase = bn + wn + nt * 16 + lhi * 4;
            f32x4 b4 = *(const f32x4*)(bias + cbase);
            int c = cbase & 1023;
#pragma unroll
            for (int mt = 0; mt < 4; ++mt) {
                int t = bm + wm + mt * 16 + llo;
                int b = t >> 11, n = t & 2047;
                f16x4 v4;
#pragma unroll
                for (int r = 0; r < 4; ++r) v4[r] = (_Float16)(acc[nt][mt][r] + b4[r]);
                *(f16x4*)(dst0 + (size_t)(b * NN + n) * DD + c) = v4;
            }
        }
    }
}

// ---------------- out-proj GEMM (exact R6: BM=64, SWAP epilogue, 24 KB LDS) ----------------
__global__ __launch_bounds__(256) void gemm_out(const _Float16* __restrict__ A,
                                                const _Float16* __restrict__ Bt,
                                                const float* __restrict__ bias,
                                                float* __restrict__ Cf) {
    const int K = DD, N = DD;
    __shared__ __align__(16) _Float16 As[64 * 64];
    __shared__ __align__(16) _Float16 Bs[128 * 64];
    int id = blockIdx.x;
    int xcd = id & 7, j = id >> 3;
    int bm = (xcd * 8 + (j >> 3)) * 64;
    int bn = (j & 7) * 128;
    int tid = threadIdx.x;
    int wave = tid >> 6, lane = tid & 63;
    int wm = (wave >> 1) * 32, wn = (wave & 1) * 64;
    int lhi = lane >> 4, llo = lane & 15;

    f32x4 acc[4][4] = {};   // [nt][mt], mt<2 used

    int srowA = wave * 16 + (lane >> 3);
    int srowB = wave * 32 + (lane >> 3);
    int scol = ((lane & 7) ^ (lane >> 3)) * 8;
    const _Float16* gA = A + (size_t)(bm + srowA) * K + scol;
    const _Float16* gB = Bt + (size_t)(bn + srowB) * K + scol;
    _Float16* lA = As + wave * 1024 + lane * 8;
    _Float16* lB = Bs + wave * 2048 + lane * 8;

    gemm_kloop<true, 2>(gA, gB, lA, lB, As, Bs, wm, wn, llo, lhi, K,
                        (f32x4(*)[4])acc);

#pragma unroll
    for (int nt = 0; nt < 4; ++nt) {
        int cbase = bn + wn + nt * 16 + lhi * 4;
        f32x4 b4 = *(const f32x4*)(bias + cbase);
#pragma unroll
        for (int mt = 0; mt < 2; ++mt) {
            int t = bm + wm + mt * 16 + llo;
            f32x4 v4;
#pragma unroll
            for (int r = 0; r < 4; ++r) v4[r] = acc[nt][mt][r] + b4[r];
            *(f32x4*)(Cf + (size_t)t * N + cbase) = v4;
        }
    }
}

// ---------------- windowed attention via MFMA (Ks/P LDS overlay: 50 KB, 3 blocks/CU) ----------------
#define KP 64
#define PP 200   // P stride: 400B (16B-aligned), rows 4 banks apart
#define VP 200
__global__ __launch_bounds__(256) void local_attn(const _Float16* __restrict__ q_h,
                                                  const _Float16* __restrict__ k_h,
                                                  const _Float16* __restrict__ vt_h,
                                                  _Float16* __restrict__ outh) {
    __shared__ __align__(16) _Float16 KsPs[64 * PP];  // 25600 B: Ks[192*64] overlaid by P[64*PP]
    __shared__ __align__(16) _Float16 Vt[64 * VP];    // 25600 B
    _Float16* Ks = KsPs;
    _Float16* Ps = KsPs;
    int tid = threadIdx.x;
    int id = blockIdx.x;
    int xcd = id & 7, j = id >> 3;
    int i0 = (xcd * 4 + (j & 3)) * 64;
    int hb = j >> 2;
    int h = hb & 15, b = hb >> 4;

    int wave = tid >> 6, lane = tid & 63;
    int llo = lane & 15, lhi = lane >> 4;

    // --- async K staging: rows j = i0-64 .. i0+127 from k_h[b][j][h*64..] ---
    {
        int srow = lane >> 3;
        int chunk = ((lane & 7) ^ (lane >> 3)) * 8;
        const _Float16* kb = k_h + (size_t)(b * NN) * DD + h * DHH + chunk;
#pragma unroll
        for (int q = 0; q < 6; ++q) {
            int p = wave * 6 + q;
            int jj = i0 - 64 + p * 8 + srow;   // may be OOR: mapped garbage, masked later
            __builtin_amdgcn_global_load_lds(AS1(kb + (ptrdiff_t)jj * DD), AS3(Ks + p * 512 + lane * 8), 16, 0, 0);
        }
    }

    // --- V^T staging: plain copy of 64 dh-rows x 192 tokens from vt_h ---
    {
        const _Float16* vb = vt_h + (size_t)((b * HH + h) * DHH) * NN + (i0 - 64);
        for (int u = tid; u < 1536; u += 256) {
            int d = u / 24, c = u % 24;
            f16x8 vv = *(const f16x8*)(vb + (ptrdiff_t)d * NN + c * 8);
            *(f16x8*)(Vt + d * VP + c * 8) = vv;
        }
    }

    // --- Q fragments straight from global ---
    int qrow = wave * 16 + llo;
    int qi = i0 + qrow;
    const _Float16* qp = q_h + (size_t)(b * NN + qi) * DD + h * DHH;
    f16x8 qf0 = *(const f16x8*)(qp + lhi * 8);
    f16x8 qf1 = *(const f16x8*)(qp + 32 + lhi * 8);
    __syncthreads();

    // --- S^T = K @ Q^T (swizzled Ks reads; row&7 == llo&7) ---
    float sc[12][4];
#pragma unroll
    for (int mt = 0; mt < 12; ++mt) {
        const _Float16* kr = Ks + (mt * 16 + llo) * 64;
        f16x8 kf0 = *(const f16x8*)(kr + ((lhi ^ (llo & 7)) * 8));
        f16x8 kf1 = *(const f16x8*)(kr + (((lhi + 4) ^ (llo & 7)) * 8));
        f32x4 a = {0.f, 0.f, 0.f, 0.f};
        a = __builtin_amdgcn_mfma_f32_16x16x32_f16(kf0, qf0, a, 0, 0, 0);
        a = __builtin_amdgcn_mfma_f32_16x16x32_f16(kf1, qf1, a, 0, 0, 0);
#pragma unroll
        for (int r = 0; r < 4; ++r) sc[mt][r] = a[r];
    }
    __syncthreads();   // all waves done reading Ks; its LDS is now P's

    // --- masked softmax over 192 slots of query qi ---
    float m = -1e30f;
#pragma unroll
    for (int mt = 0; mt < 12; ++mt)
#pragma unroll
        for (int r = 0; r < 4; ++r) {
            int sidx = mt * 16 + lhi * 4 + r;
            int jj = i0 - 64 + sidx;
            int dj = jj - qi;
            bool valid = (jj >= 0) && (jj < NN) && (dj <= 64) && (dj >= -64);
            float v = valid ? sc[mt][r] * SCALE : -1e30f;   // select: garbage never propagates
            sc[mt][r] = v;
            m = fmaxf(m, v);
        }
    m = fmaxf(m, __shfl_xor(m, 16, 64));
    m = fmaxf(m, __shfl_xor(m, 32, 64));
    float l = 0.f;
#pragma unroll
    for (int mt = 0; mt < 12; ++mt)
#pragma unroll
        for (int r = 0; r < 4; ++r) {
            float e = __expf(sc[mt][r] - m);
            sc[mt][r] = e;
            l += e;
        }
    l += __shfl_xor(l, 16, 64);
    l += __shfl_xor(l, 32, 64);
    float invl = 1.f / l;

    // --- write normalized P rows (overlays Ks; own rows -> wave-local wait) ---
#pragma unroll
    for (int mt = 0; mt < 12; ++mt) {
        f16x4 pv;
#pragma unroll
        for (int r = 0; r < 4; ++r) pv[r] = (_Float16)(sc[mt][r] * invl);
        *(f16x4*)(Ps + qrow * PP + mt * 16 + lhi * 4) = pv;
    }
    __asm__ volatile("s_waitcnt lgkmcnt(0)" ::: "memory");  // wave-local P write->read

    // --- O = P @ V ---
    f32x4 oacc[4] = {};
#pragma unroll
    for (int ks = 0; ks < 6; ++ks) {
        f16x8 pf = *(const f16x8*)(Ps + (wave * 16 + llo) * PP + ks * 32 + lhi * 8);
#pragma unroll
        for (int nt = 0; nt < 4; ++nt) {
            f16x8 vf = *(const f16x8*)(Vt + (nt * 16 + llo) * VP + ks * 32 + lhi * 8);
            oacc[nt] = __builtin_amdgcn_mfma_f32_16x16x32_f16(pf, vf, oacc[nt], 0, 0, 0);
        }
    }

    // --- epilogue: col=llo=dh, row=lhi*4+r=query ---
    _Float16* orow = outh + (size_t)(b * NN) * DD + h * DHH;
#pragma unroll
    for (int nt = 0; nt < 4; ++nt)
#pragma unroll
        for (int r = 0; r < 4; ++r) {
            int q = wave * 16 + lhi * 4 + r;
            int d = nt * 16 + llo;
            orow[(size_t)(i0 + q) * DD + d] = (_Float16)oacc[nt][r];
        }
}

// ---------------- launch ----------------
extern "C" void kernel_launch(void* const* d_in, const int* in_sizes, int n_in,
                              void* d_out, int out_size, void* d_ws, size_t ws_size,
                              hipStream_t stream) {
    const float* x    = (const float*)d_in[0];
    const float* Wqkv = (const float*)d_in[1];
    const float* bqkv = (const float*)d_in[2];
    const float* Wout = (const float*)d_in[3];
    const float* bout = (const float*)d_in[4];
    float* out = (float*)d_out;

    char* ws = (char*)d_ws;
    _Float16* x_h    = (_Float16*)(ws);                              //  8 MB [4096][1024]
    _Float16* Wqkv_t = (_Float16*)(ws + (size_t)8  * 1024 * 1024);   //  6 MB [3072][1024]
    _Float16* Wout_t = (_Float16*)(ws + (size_t)14 * 1024 * 1024);   //  2 MB [1024][1024]
    _Float16* q_h    = (_Float16*)(ws + (size_t)16 * 1024 * 1024);   //  8 MB [2][2048][1024]
    _Float16* k_h    = (_Float16*)(ws + (size_t)24 * 1024 * 1024);   //  8 MB [2][2048][1024]
    _Float16* vt_h   = (_Float16*)(ws + (size_t)32 * 1024 * 1024);   //  8 MB [2*16*64][2048]
    _Float16* attn_h = (_Float16*)(ws + (size_t)40 * 1024 * 1024);   //  8 MB [4096][1024]

    prep<<<6144, 256, 0, stream>>>(x, x_h, Wqkv, Wqkv_t, Wout, Wout_t);

    gemm_qkv<<<768, 256, 0, stream>>>(x_h, Wqkv_t, bqkv, q_h, k_h, vt_h);

    local_attn<<<1024, 256, 0, stream>>>(q_h, k_h, vt_h, attn_h);

    gemm_out<<<512, 256, 0, stream>>>(attn_h, Wout_t, bout, out);
}